// Round 3
// baseline (371.915 us; speedup 1.0000x reference)
//
#include <hip/hip_runtime.h>

// Segment mean pooling: out[s, :] = mean(x[pointer[s]:pointer[s+1], :])
// x: [524288, 128] f32, pointer: [1025] i32, out: [1024, 128] f32.
//
// Flat, load-balanced decomposition: every block sums exactly 512 contiguous
// rows; every wave owns 128 consecutive rows. Lanes 0-31 hold row r, lanes
// 32-63 hold row r+1, so each global_load_dwordx4 is ONE contiguous 1 KB
// request; 16 loads (16 KB) are kept in flight per wave. Partial sums are
// scaled by 1/count and combined with HW fp32 atomics into zeroed d_out.

constexpr int kNodes        = 524288;
constexpr int kGraphs       = 1024;
constexpr int kFeat         = 128;
constexpr int kQuads        = kFeat / 4;   // 32 float4 per row
constexpr int kBlock        = 256;
constexpr int kBlocks       = 1024;
constexpr int kRowsPerBlock = kNodes / kBlocks;   // 512
constexpr int kRowsPerWave  = kRowsPerBlock / 4;  // 128

__global__ __launch_bounds__(kBlock, 4) void seg_mean_kernel(
    const float* __restrict__ x,
    const int* __restrict__ pointer,
    float* __restrict__ out) {
  __shared__ int sp[kGraphs + 1];
  for (int i = threadIdx.x; i <= kGraphs; i += kBlock) sp[i] = pointer[i];
  __syncthreads();

  const int wave = threadIdx.x >> 6;   // 0..3
  const int lane = threadIdx.x & 63;
  const int par  = lane >> 5;          // row parity within a row pair
  const int q    = lane & 31;          // float4 column within the row
  const int W0   = blockIdx.x * kRowsPerBlock + wave * kRowsPerWave;
  const int wend = W0 + kRowsPerWave;

  // This half-wave processes rows r = W0 + par, W0 + par + 2, ... (< wend).
  int r = W0 + par;

  // seg = max i in [0, kGraphs-1] with sp[i] <= r (searchsorted-right - 1;
  // handles duplicate pointer values / empty segments). Uniform per half-wave.
  int lo = 0, hi = kGraphs - 1;
  while (lo < hi) {
    int mid = (lo + hi + 1) >> 1;
    if (sp[mid] <= r) lo = mid; else hi = mid - 1;
  }
  int seg  = lo;
  int next = sp[seg + 1];   // > r by construction of the search

  const float4* __restrict__ xv = reinterpret_cast<const float4*>(x);
  float ax = 0.f, ay = 0.f, az = 0.f, aw = 0.f;

  while (r < wend) {
    // Crossed one (or more, if empty segments) boundaries: flush and advance.
    while (r >= next) {
      const int   cnt = next - sp[seg];
      const float inv = 1.0f / (float)(cnt > 0 ? cnt : 1);
      float* o = out + (size_t)seg * kFeat + (q << 2);
      unsafeAtomicAdd(o + 0, ax * inv);
      unsafeAtomicAdd(o + 1, ay * inv);
      unsafeAtomicAdd(o + 2, az * inv);
      unsafeAtomicAdd(o + 3, aw * inv);
      ax = ay = az = aw = 0.f;
      ++seg;
      next = sp[seg + 1];
    }
    const int stop = next < wend ? next : wend;  // rows [r, stop) all in seg
    const float4* p = xv + (size_t)r * kQuads + q;
    // Fast path: 16 stride-2 rows (span 32 rows); 16 contiguous-1KB loads in
    // flight per wave for latency hiding.
    for (; r + 30 < stop; r += 32, p += 32 * kQuads) {
      const float4 v0  = p[0 * 2 * kQuads];
      const float4 v1  = p[1 * 2 * kQuads];
      const float4 v2  = p[2 * 2 * kQuads];
      const float4 v3  = p[3 * 2 * kQuads];
      const float4 v4  = p[4 * 2 * kQuads];
      const float4 v5  = p[5 * 2 * kQuads];
      const float4 v6  = p[6 * 2 * kQuads];
      const float4 v7  = p[7 * 2 * kQuads];
      const float4 v8  = p[8 * 2 * kQuads];
      const float4 v9  = p[9 * 2 * kQuads];
      const float4 v10 = p[10 * 2 * kQuads];
      const float4 v11 = p[11 * 2 * kQuads];
      const float4 v12 = p[12 * 2 * kQuads];
      const float4 v13 = p[13 * 2 * kQuads];
      const float4 v14 = p[14 * 2 * kQuads];
      const float4 v15 = p[15 * 2 * kQuads];
      ax += v0.x;  ay += v0.y;  az += v0.z;  aw += v0.w;
      ax += v1.x;  ay += v1.y;  az += v1.z;  aw += v1.w;
      ax += v2.x;  ay += v2.y;  az += v2.z;  aw += v2.w;
      ax += v3.x;  ay += v3.y;  az += v3.z;  aw += v3.w;
      ax += v4.x;  ay += v4.y;  az += v4.z;  aw += v4.w;
      ax += v5.x;  ay += v5.y;  az += v5.z;  aw += v5.w;
      ax += v6.x;  ay += v6.y;  az += v6.z;  aw += v6.w;
      ax += v7.x;  ay += v7.y;  az += v7.z;  aw += v7.w;
      ax += v8.x;  ay += v8.y;  az += v8.z;  aw += v8.w;
      ax += v9.x;  ay += v9.y;  az += v9.z;  aw += v9.w;
      ax += v10.x; ay += v10.y; az += v10.z; aw += v10.w;
      ax += v11.x; ay += v11.y; az += v11.z; aw += v11.w;
      ax += v12.x; ay += v12.y; az += v12.z; aw += v12.w;
      ax += v13.x; ay += v13.y; az += v13.z; aw += v13.w;
      ax += v14.x; ay += v14.y; az += v14.z; aw += v14.w;
      ax += v15.x; ay += v15.y; az += v15.z; aw += v15.w;
    }
    // Tail: remaining stride-2 rows of this segment run.
    for (; r < stop; r += 2, p += 2 * kQuads) {
      const float4 v = p[0];
      ax += v.x; ay += v.y; az += v.z; aw += v.w;
    }
  }

  // Final flush for the segment containing this half-wave's last row.
  {
    const int   cnt = next - sp[seg];
    const float inv = 1.0f / (float)(cnt > 0 ? cnt : 1);
    float* o = out + (size_t)seg * kFeat + (q << 2);
    unsafeAtomicAdd(o + 0, ax * inv);
    unsafeAtomicAdd(o + 1, ay * inv);
    unsafeAtomicAdd(o + 2, az * inv);
    unsafeAtomicAdd(o + 3, aw * inv);
  }
}

extern "C" void kernel_launch(void* const* d_in, const int* in_sizes, int n_in,
                              void* d_out, int out_size, void* d_ws, size_t ws_size,
                              hipStream_t stream) {
  const float* x       = (const float*)d_in[0];
  const int*   pointer = (const int*)d_in[1];
  float*       out     = (float*)d_out;

  // Harness poisons d_out with 0xAA before every launch; atomics need zeros.
  hipMemsetAsync(out, 0, (size_t)out_size * sizeof(float), stream);
  seg_mean_kernel<<<kBlocks, kBlock, 0, stream>>>(x, pointer, out);
}